// Round 13
// baseline (363.715 us; speedup 1.0000x reference)
//
#include <hip/hip_runtime.h>
#include <hip/hip_bf16.h>

// Problem constants: B=2, N=2048, C=768, H=12, HD=64
typedef __bf16 bf8 __attribute__((ext_vector_type(8)));
typedef float f4 __attribute__((ext_vector_type(4)));

__device__ __forceinline__ unsigned short f2b(float f) {
  union { __hip_bfloat16 h; unsigned short u; } cv;
  cv.h = __float2bfloat16(f);
  return cv.u;
}

__device__ __forceinline__ float b2f(unsigned short u) {
  union { unsigned int u; float f; } cv;
  cv.u = ((unsigned int)u) << 16;
  return cv.f;
}

__device__ __forceinline__ f4 mfma16(bf8 a, bf8 b, f4 c) {
  return __builtin_amdgcn_mfma_f32_16x16x32_bf16(a, b, c, 0, 0, 0);
}

// ---------------- merged: x->bf16 + mask/bias prep (bid<3097) | weight transposes ------
__global__ void k_prept(const float* __restrict__ x, unsigned short* __restrict__ xb,
                        const void* __restrict__ mraw, const float* __restrict__ bq,
                        const float* __restrict__ bkv, float* __restrict__ maskbias,
                        float* __restrict__ biasc,
                        const float* __restrict__ Wq, const float* __restrict__ Wkv,
                        const float* __restrict__ Wp, unsigned short* __restrict__ Wct,
                        unsigned short* __restrict__ Wpt) {
  __shared__ float tile[32][33];
  const int bid = blockIdx.x;
  if (bid < 3072) {
    size_t t = (size_t)bid * 256 + threadIdx.x;
    float4 v = *(const float4*)(x + t * 4);
    ushort4 o;
    o.x = f2b(v.x); o.y = f2b(v.y); o.z = f2b(v.z); o.w = f2b(v.w);
    *(ushort4*)(xb + t * 4) = o;
    return;
  }
  if (bid < 3097) {
    int t = (bid - 3072) * 256 + threadIdx.x;
    const unsigned char* pb = (const unsigned char*)mraw;
    const unsigned int* pd = (const unsigned int*)mraw;
    int isfloat = 0, isbyte = 0;
    for (int i = 0; i < 128; ++i) {   // 512 bytes, safe for bool/int32/f32 mask dtypes
      unsigned int d = pd[i];
      if (d == 0x3f800000u) isfloat = 1;
      if ((d & 0xffffff00u) != 0u && d != 0x3f800000u) isbyte = 1;
    }
    if (t < 4096) {
      int v;
      if (isbyte)       v = pb[t];
      else if (isfloat) v = (((const float*)mraw)[t] != 0.0f);
      else              v = ((const int*)mraw)[t];
      maskbias[t] = v ? 0.0f : -1e30f;
    } else if (t < 4096 + 2304) {
      int j = t - 4096;
      biasc[j] = (j < 768) ? bq[j] : bkv[j - 768];
    }
    return;
  }
  // transpose3: fp32 [R][Cc] -> bf16 [Cc][R]
  int id = bid - 3097;
  int bx = id % 96, by = id / 96;
  const float* in; unsigned short* out; int Cc, bxl;
  if (bx < 24)      { in = Wq;  out = Wct;                         Cc = 768;  bxl = bx; }
  else if (bx < 72) { in = Wkv; out = Wct + (size_t)768 * 768;     Cc = 1536; bxl = bx - 24; }
  else              { in = Wp;  out = Wpt;                         Cc = 768;  bxl = bx - 72; }
  const int R = 768;
  int c0 = bxl * 32, r0 = by * 32;
  int tx = threadIdx.x & 31, ty = threadIdx.x >> 5;
  for (int j = 0; j < 32; j += 8)
    tile[ty + j][tx] = in[(size_t)(r0 + ty + j) * Cc + c0 + tx];
  __syncthreads();
  for (int j = 0; j < 32; j += 8)
    out[(size_t)(c0 + ty + j) * R + r0 + tx] = f2b(tile[tx][ty + j]);
}

// ---------------- bf16 GEMM: A[M][K] @ Bt[N][K]^T, 128x128 tile, 4 waves ----------------
// BARRIER-FREE k-loop: fragments loaded 16B/lane straight from global (L2-served,
// same pattern as k_pv's A-path); no LDS staging, no vmcnt drains until epilogue.
// MODE 0: QKV projection -> q,k,v all [b][h][n][hd] bf16 (+bias), coalesced LDS re-stage
// MODE 1: out projection -> fp32 d_out [row][col] (+bias), reg-direct float4
template<int MODE>
__global__ __launch_bounds__(256) void k_gemm(
    const unsigned short* __restrict__ A,
    const unsigned short* __restrict__ Bt,
    const float* __restrict__ bias,
    float* __restrict__ outf,
    unsigned short* __restrict__ qo,
    unsigned short* __restrict__ ko,
    unsigned short* __restrict__ vo,
    int K)
{
  __shared__ unsigned short sm[(MODE == 0) ? 128 * 136 : 64];
  const int tid = threadIdx.x;
  const int w = tid >> 6, l = tid & 63;
  const int wr = w >> 1, wc = w & 1;
  const int m0 = blockIdx.y * 128, n0 = blockIdx.x * 128;
  const int fr = l & 15, fk = (l >> 4) * 8;
  f4 acc[4][4] = {};

  for (int k0 = 0; k0 < K; k0 += 32) {
    bf8 af[4], bfv[4];
#pragma unroll
    for (int i = 0; i < 4; ++i)
      af[i]  = *(const bf8*)(A  + (size_t)(m0 + wr * 64 + i * 16 + fr) * K + k0 + fk);
#pragma unroll
    for (int i = 0; i < 4; ++i)
      bfv[i] = *(const bf8*)(Bt + (size_t)(n0 + wc * 64 + i * 16 + fr) * K + k0 + fk);
#pragma unroll
    for (int i = 0; i < 4; ++i)
#pragma unroll
      for (int j2 = 0; j2 < 4; ++j2)
        acc[i][j2] = mfma16(af[i], bfv[j2], acc[i][j2]);
  }

  const int fg = l >> 4;
  if constexpr (MODE == 1) {
#pragma unroll
    for (int j2 = 0; j2 < 4; ++j2) {
      int col = n0 + wc * 64 + j2 * 16 + fr;
      float bv = bias[col];
#pragma unroll
      for (int i = 0; i < 4; ++i) {
        int rbase = m0 + wr * 64 + i * 16 + fg * 4;
#pragma unroll
        for (int r = 0; r < 4; ++r)
          outf[(size_t)(rbase + r) * 768 + col] = acc[i][j2][r] + bv;
      }
    }
  } else {
    // stage tile to LDS bf16 [128][136], then coalesced 16B stores per layout
#pragma unroll
    for (int j2 = 0; j2 < 4; ++j2) {
      int colc = wc * 64 + j2 * 16 + fr;
      float bv = bias[n0 + colc];
#pragma unroll
      for (int i = 0; i < 4; ++i)
#pragma unroll
        for (int r = 0; r < 4; ++r)
          sm[(wr * 64 + i * 16 + fg * 4 + r) * 136 + colc] = f2b(acc[i][j2][r] + bv);
    }
    __syncthreads();
#pragma unroll
    for (int it = 0; it < 8; ++it) {
      int flat = it * 2048 + tid * 8;
      int rl = flat >> 7, mc = flat & 127;
      int row = m0 + rl, col = n0 + mc;
      bf8 v = *(const bf8*)&sm[rl * 136 + mc];
      int b = row >> 11, n = row & 2047;
      unsigned short* dst;
      if (col < 768)        { int h = col >> 6;
        dst = qo + (((size_t)b * 12 + h) * 2048 + n) * 64 + (col & 63); }
      else if (col < 1536)  { int c2 = col - 768;  int h = c2 >> 6;
        dst = ko + (((size_t)b * 12 + h) * 2048 + n) * 64 + (c2 & 63); }
      else                  { int c2 = col - 1536; int h = c2 >> 6;
        dst = vo + (((size_t)b * 12 + h) * 2048 + n) * 64 + (c2 & 63); }
      *(bf8*)dst = v;
    }
  }
}

// ---------------- merged: P producer (bid<6144) | V transpose (else) ----------------
// pexp: S=QK^T, BARRIER-FREE k-loop (direct-global frags), epilogue exp -> Pws bf16
// via coalesced LDS re-stage + Lpart row-sums (R11 epilogue verbatim).
// trv: bf16 V[bh][2048][64] -> vT[bh][64][2048].
__global__ __launch_bounds__(256) void k_pexptrv(
    const unsigned short* __restrict__ q,
    const unsigned short* __restrict__ kk,
    const float* __restrict__ maskbias,
    unsigned short* __restrict__ Pws,
    float* __restrict__ Lpart,
    const unsigned short* __restrict__ v,
    unsigned short* __restrict__ vT)
{
  __shared__ unsigned short sm[128 * 136];     // pexp epilogue; trv uses first 1056
  const int bid = blockIdx.x;
  const int tid = threadIdx.x;
  if (bid >= 6144) {
    // trv: id = bx + 2*by + 128*bz  (bx<2, by<64, bz<24)
    int id = bid - 6144;
    int bx = id & 1, by = (id >> 1) & 63, bz = id >> 7;
    int tx = tid & 31, ty = tid >> 5;
    const unsigned short* src = v + (size_t)bz * 131072;
    unsigned short* dst = vT + (size_t)bz * 131072;
    for (int j = 0; j < 32; j += 8)
      sm[(ty + j) * 33 + tx] = src[(size_t)(by * 32 + ty + j) * 64 + bx * 32 + tx];
    __syncthreads();
    for (int j = 0; j < 32; j += 8)
      dst[(size_t)(bx * 32 + ty + j) * 2048 + by * 32 + tx] = sm[tx * 33 + ty + j];
    return;
  }
  const int w = tid >> 6, l = tid & 63;
  const int wr = w >> 1, wc = w & 1;
  const int mt = bid & 15, nt = (bid >> 4) & 15, bh = bid >> 8;
  const int b = bh / 12;
  const int n0 = nt * 128, m0 = mt * 128;
  const int fr = l & 15, fg = l >> 4, fk = fg * 8;
  const unsigned short* qh = q + (size_t)bh * 2048 * 64;
  const unsigned short* kh = kk + (size_t)bh * 2048 * 64;
  f4 acc[4][4] = {};

#pragma unroll
  for (int k0 = 0; k0 < 64; k0 += 32) {
    bf8 af[4], bfv[4];
#pragma unroll
    for (int i = 0; i < 4; ++i)
      af[i]  = *(const bf8*)(qh + (size_t)(n0 + wr * 64 + i * 16 + fr) * 64 + k0 + fk);
#pragma unroll
    for (int i = 0; i < 4; ++i)
      bfv[i] = *(const bf8*)(kh + (size_t)(m0 + wc * 64 + i * 16 + fr) * 64 + k0 + fk);
#pragma unroll
    for (int i = 0; i < 4; ++i)
#pragma unroll
      for (int j2 = 0; j2 < 4; ++j2)
        acc[i][j2] = mfma16(af[i], bfv[j2], acc[i][j2]);
  }

  // epilogue: p = exp(s*scale + mb); stage into sm[128][136]; row-sum -> Lpart
  const float scale = 0.125f;
  const float* mbp = maskbias + b * 2048 + m0;
#pragma unroll
  for (int i = 0; i < 4; ++i) {
#pragma unroll
    for (int r = 0; r < 4; ++r) {
      int nl = wr * 64 + i * 16 + fg * 4 + r;
      float rs = 0.0f;
#pragma unroll
      for (int j2 = 0; j2 < 4; ++j2) {
        int ml = wc * 64 + j2 * 16 + fr;
        float p = __expf(fmaf(acc[i][j2][r], scale, mbp[ml]));
        rs += p;
        sm[nl * 136 + ml] = f2b(p);
      }
      rs += __shfl_xor(rs, 1);
      rs += __shfl_xor(rs, 2);
      rs += __shfl_xor(rs, 4);
      rs += __shfl_xor(rs, 8);
      if (fr == 0)
        Lpart[((size_t)bh * 32 + mt * 2 + wc) * 2048 + n0 + nl] = rs;
    }
  }
  __syncthreads();
  // coalesced bf16 write: 8 iters x 256 thr x 8 shorts = 128x128 tile
#pragma unroll
  for (int it = 0; it < 8; ++it) {
    int flat = it * 2048 + tid * 8;
    int row = flat >> 7, mc = flat & 127;
    bf8 vv = *(const bf8*)&sm[row * 136 + mc];
    *(bf8*)(Pws + ((size_t)bh * 2048 + n0 + row) * 2048 + m0 + mc) = vv;
  }
}

// ---------------- reduce 32 L slices -> iL ----------------
__global__ void k_lred(const float* __restrict__ Lpart, float* __restrict__ iLst) {
  int t = blockIdx.x * 256 + threadIdx.x;   // 49152 = 24 bh x 2048 n
  int bh = t >> 11, n = t & 2047;
  float s = 0.0f;
#pragma unroll
  for (int sl = 0; sl < 32; ++sl)
    s += Lpart[((size_t)bh * 32 + sl) * 2048 + n];
  iLst[t] = 1.0f / fmaxf(s, 1e-30f);
}

// ---------------- merged: PV (bid<768) | att writer (else) ----------------
// pv blocks dispatched FIRST -> resident from t=0, MFMA overlaps attw's BW streaming.
__global__ __launch_bounds__(256) void k_attwpv(
    const unsigned short* __restrict__ Pws,
    const float* __restrict__ iLst,
    float* __restrict__ att,
    const unsigned short* __restrict__ vT,
    unsigned short* __restrict__ ao)
{
  __shared__ unsigned short smem[6656];
  const int bid = blockIdx.x;
  const int tid = threadIdx.x;
  const int w = tid >> 6, l = tid & 63;

  if (bid < 768) {
    // ---- PV: O = P @ V, ks=1, iL folded, writes ao bf16 directly ----
    unsigned short* B0 = smem;            // [64*32]
    unsigned short* B1 = smem + 2048;     // [64*32]
    const int bh = bid % 24, nt = bid / 24;
    const int b = bh / 12, h = bh % 12;
    const int n0 = nt * 64;
    const int lr = l >> 2, lc = (l & 3) * 8;
    const int fr = l & 15, fg = l >> 4, fk = fg * 8;
    const unsigned short* Ph = Pws + (size_t)bh * 2048 * 2048
                             + (size_t)(n0 + w * 16 + fr) * 2048 + fk;
    const unsigned short* vh = vT + (size_t)bh * 64 * 2048;
    f4 acc[4] = {};

    for (int k0 = 0; k0 < 2048; k0 += 64) {
#if __has_builtin(__builtin_amdgcn_global_load_lds)
      __builtin_amdgcn_global_load_lds(
          (const __attribute__((address_space(1))) void*)(vh + (size_t)(w * 16 + lr) * 2048 + k0 + lc),
          (__attribute__((address_space(3))) void*)&B0[(w * 16) * 32], 16, 0, 0);
      __builtin_amdgcn_global_load_lds(
          (const __attribute__((address_space(1))) void*)(vh + (size_t)(w * 16 + lr) * 2048 + k0 + 32 + lc),
          (__attribute__((address_space(3))) void*)&B1[(w * 16) * 32], 16, 0, 0);
#else
      *(bf8*)((char*)&B0[(w * 16) * 32] + l * 16) = *(const bf8*)(vh + (size_t)(w * 16 + lr) * 2048 + k0 + lc);
      *(bf8*)((char*)&B1[(w * 16) * 32] + l * 16) = *(const bf8*)(vh + (size_t)(w * 16 + lr) * 2048 + k0 + 32 + lc);
#endif
      bf8 a0 = *(const bf8*)(Ph + k0);
      bf8 a1 = *(const bf8*)(Ph + k0 + 32);
      asm volatile("s_waitcnt vmcnt(0)" ::: "memory");
      __syncthreads();
#pragma unroll
      for (int j2 = 0; j2 < 4; ++j2) {
        bf8 bv = *(const bf8*)&B0[(j2 * 16 + fr) * 32 + fk];
        acc[j2] = mfma16(a0, bv, acc[j2]);
      }
#pragma unroll
      for (int j2 = 0; j2 < 4; ++j2) {
        bf8 bv = *(const bf8*)&B1[(j2 * 16 + fr) * 32 + fk];
        acc[j2] = mfma16(a1, bv, acc[j2]);
      }
      __syncthreads();
    }

    float il[4];
#pragma unroll
    for (int r = 0; r < 4; ++r)
      il[r] = iLst[(size_t)bh * 2048 + n0 + w * 16 + fg * 4 + r];
#pragma unroll
    for (int j2 = 0; j2 < 4; ++j2)
#pragma unroll
      for (int r = 0; r < 4; ++r)
        ao[((size_t)(b * 2048) + n0 + w * 16 + fg * 4 + r) * 768 + h * 64 + j2 * 16 + fr]
            = f2b(acc[j2][r] * il[r]);
    return;
  }

  // ---- att writer: barrier-free transpose-stream, bf16 slab ----
  const int idx = (bid - 768) * 4 + w;      // = b*4096 + n*2 + half
  const int b = idx >> 12;
  const int n = (idx >> 1) & 2047;
  const int half = idx & 1;
  const int hq = l >> 4, mg = l & 15;
  unsigned short* sl = smem + w * 1664;

  float iLv[3];
#pragma unroll
  for (int g = 0; g < 3; ++g)
    iLv[g] = iLst[((size_t)(b * 12 + g * 4 + hq)) * 2048 + n];

  for (int c = 0; c < 8; ++c) {
    const int m0 = half * 1024 + c * 128;
#pragma unroll
    for (int g = 0; g < 3; ++g) {
      int h = g * 4 + hq;
      bf8 pv = *(const bf8*)(Pws + ((size_t)(b * 12 + h) * 2048 + n) * 2048 + m0 + mg * 8);
      const unsigned short* pu = (const unsigned short*)&pv;
      // element (m, h) at sl[(m>>3)*104 + (m&7)*12 + h]; m = mg*8+j
#pragma unroll
      for (int j = 0; j < 8; ++j)
        sl[mg * 104 + j * 12 + h] = f2b(b2f(pu[j]) * iLv[g]);
    }
    // same-wave LDS RAW: compiler inserts lgkmcnt waits
    float* dst = att + (((size_t)(b * 2048 + n)) * 2048 + m0) * 12;
#pragma unroll
    for (int it = 0; it < 6; ++it) {
      int f = it * 256 + l * 4;
      int sa = (f / 96) * 104 + f % 96;
      ushort4 s4 = *(const ushort4*)&sl[sa];
      f4 v = {b2f(s4.x), b2f(s4.y), b2f(s4.z), b2f(s4.w)};
      *(f4*)(dst + f) = v;
    }
  }
}

extern "C" void kernel_launch(void* const* d_in, const int* in_sizes, int n_in,
                              void* d_out, int out_size, void* d_ws, size_t ws_size,
                              hipStream_t stream) {
  const float* x   = (const float*)d_in[0];
  const void*  msk = d_in[1];
  const float* Wq  = (const float*)d_in[2];
  const float* bq  = (const float*)d_in[3];
  const float* Wkv = (const float*)d_in[4];
  const float* bkv = (const float*)d_in[5];
  const float* Wp  = (const float*)d_in[6];
  const float* bp  = (const float*)d_in[7];
  float* out = (float*)d_out;
  float* att = out + (size_t)2 * 2048 * 768;

  char* ws = (char*)d_ws;
  float* maskbias = (float*)ws;                      // 4096 f32
  float* biasc    = maskbias + 4096;                 // 2304 f32
  unsigned short* xb  = (unsigned short*)(ws + 32768);
  unsigned short* Wct = xb  + (size_t)4096 * 768;    // [2304][768]
  unsigned short* Wpt = Wct + (size_t)2304 * 768;    // [768][768]
  unsigned short* qb  = Wpt + (size_t)768 * 768;     // [2][12][2048][64]
  unsigned short* kb  = qb  + (size_t)3145728;
  unsigned short* vb  = kb  + (size_t)3145728;       // [2][12][2048][64]
  unsigned short* vTb = vb  + (size_t)3145728;       // [2][12][64][2048]
  float* iLstat = (float*)(vTb + (size_t)3145728);   // [24][2048]
  float* Lpart  = iLstat + 49152;                    // [24][32][2048] f32, 6.3MB
  unsigned short* Pws = (unsigned short*)(Lpart + (size_t)24 * 32 * 2048); // [24][2048][2048] bf16, 201MB
  unsigned short* ao = xb;                           // overlay: xb dead after k_gemm<0>

  k_prept<<<dim3(5401), dim3(256), 0, stream>>>(x, xb, msk, bq, bkv, maskbias, biasc,
                                                Wq, Wkv, Wp, Wct, Wpt);
  k_gemm<0><<<dim3(18, 32), dim3(256), 0, stream>>>(xb, Wct, biasc, nullptr, qb, kb, vb, 768);
  k_pexptrv<<<dim3(9216), dim3(256), 0, stream>>>(qb, kb, maskbias, Pws, Lpart, vb, vTb);
  k_lred<<<dim3(192), dim3(256), 0, stream>>>(Lpart, iLstat);
  k_attwpv<<<dim3(2816), dim3(256), 0, stream>>>(Pws, iLstat, att, vTb, ao);
  k_gemm<1><<<dim3(6, 32), dim3(256), 0, stream>>>(ao, Wpt, bp, out, nullptr, nullptr, nullptr, 768);
}

// Round 14
// 246.215 us; speedup vs baseline: 1.4772x; 1.4772x over previous
//
#include <hip/hip_runtime.h>
#include <hip/hip_bf16.h>

// Problem constants: B=2, N=2048, C=768, H=12, HD=64
typedef __bf16 bf8 __attribute__((ext_vector_type(8)));
typedef float f4 __attribute__((ext_vector_type(4)));

__device__ __forceinline__ unsigned short f2b(float f) {
  union { __hip_bfloat16 h; unsigned short u; } cv;
  cv.h = __float2bfloat16(f);
  return cv.u;
}

__device__ __forceinline__ float b2f(unsigned short u) {
  union { unsigned int u; float f; } cv;
  cv.u = ((unsigned int)u) << 16;
  return cv.f;
}

__device__ __forceinline__ f4 mfma16(bf8 a, bf8 b, f4 c) {
  return __builtin_amdgcn_mfma_f32_16x16x32_bf16(a, b, c, 0, 0, 0);
}

// async global->LDS staging, 16B per lane; lds base must be wave-uniform
__device__ __forceinline__ void stage16(const unsigned short* g, unsigned short* lbase, int lane) {
#if __has_builtin(__builtin_amdgcn_global_load_lds)
  __builtin_amdgcn_global_load_lds((const __attribute__((address_space(1))) void*)g,
                                   (__attribute__((address_space(3))) void*)lbase, 16, 0, 0);
#else
  *(bf8*)((char*)lbase + lane * 16) = *(const bf8*)g;
#endif
}

// ---------------- merged: x->bf16 + mask/bias prep (bid<3097) | weight transposes ------
__global__ void k_prept(const float* __restrict__ x, unsigned short* __restrict__ xb,
                        const void* __restrict__ mraw, const float* __restrict__ bq,
                        const float* __restrict__ bkv, float* __restrict__ maskbias,
                        float* __restrict__ biasc,
                        const float* __restrict__ Wq, const float* __restrict__ Wkv,
                        const float* __restrict__ Wp, unsigned short* __restrict__ Wct,
                        unsigned short* __restrict__ Wpt) {
  __shared__ float tile[32][33];
  const int bid = blockIdx.x;
  if (bid < 3072) {
    size_t t = (size_t)bid * 256 + threadIdx.x;
    float4 v = *(const float4*)(x + t * 4);
    ushort4 o;
    o.x = f2b(v.x); o.y = f2b(v.y); o.z = f2b(v.z); o.w = f2b(v.w);
    *(ushort4*)(xb + t * 4) = o;
    return;
  }
  if (bid < 3097) {
    int t = (bid - 3072) * 256 + threadIdx.x;
    const unsigned char* pb = (const unsigned char*)mraw;
    const unsigned int* pd = (const unsigned int*)mraw;
    int isfloat = 0, isbyte = 0;
    for (int i = 0; i < 128; ++i) {   // 512 bytes, safe for bool/int32/f32 mask dtypes
      unsigned int d = pd[i];
      if (d == 0x3f800000u) isfloat = 1;
      if ((d & 0xffffff00u) != 0u && d != 0x3f800000u) isbyte = 1;
    }
    if (t < 4096) {
      int v;
      if (isbyte)       v = pb[t];
      else if (isfloat) v = (((const float*)mraw)[t] != 0.0f);
      else              v = ((const int*)mraw)[t];
      maskbias[t] = v ? 0.0f : -1e30f;
    } else if (t < 4096 + 2304) {
      int j = t - 4096;
      biasc[j] = (j < 768) ? bq[j] : bkv[j - 768];
    }
    return;
  }
  // transpose3: fp32 [R][Cc] -> bf16 [Cc][R]
  int id = bid - 3097;
  int bx = id % 96, by = id / 96;
  const float* in; unsigned short* out; int Cc, bxl;
  if (bx < 24)      { in = Wq;  out = Wct;                         Cc = 768;  bxl = bx; }
  else if (bx < 72) { in = Wkv; out = Wct + (size_t)768 * 768;     Cc = 1536; bxl = bx - 24; }
  else              { in = Wp;  out = Wpt;                         Cc = 768;  bxl = bx - 72; }
  const int R = 768;
  int c0 = bxl * 32, r0 = by * 32;
  int tx = threadIdx.x & 31, ty = threadIdx.x >> 5;
  for (int j = 0; j < 32; j += 8)
    tile[ty + j][tx] = in[(size_t)(r0 + ty + j) * Cc + c0 + tx];
  __syncthreads();
  for (int j = 0; j < 32; j += 8)
    out[(size_t)(c0 + ty + j) * R + r0 + tx] = f2b(tile[tx][ty + j]);
}

// ---------------- bf16 GEMM: A[M][K] @ Bt[N][K]^T, 128x128 tile, 4 waves (R9) -----------
// MODE 0: QKV projection -> q,k,v all [b][h][n][hd] bf16 (+bias), coalesced via LDS re-stage
// MODE 1: out projection -> fp32 d_out [row][col] (+bias), nontemporal stores
template<int MODE>
__global__ __launch_bounds__(256) void k_gemm(
    const unsigned short* __restrict__ A,
    const unsigned short* __restrict__ Bt,
    const float* __restrict__ bias,
    float* __restrict__ outf,
    unsigned short* __restrict__ qo,
    unsigned short* __restrict__ ko,
    unsigned short* __restrict__ vo,
    int K)
{
  __shared__ unsigned short sm[128 * 136];   // k-loop: As=sm[0..4095], Bs=sm[4096..8191]
  unsigned short* As = sm;
  unsigned short* Bs = sm + 4096;
  const int tid = threadIdx.x;
  const int w = tid >> 6, l = tid & 63;
  const int wr = w >> 1, wc = w & 1;
  const int m0 = blockIdx.y * 128, n0 = blockIdx.x * 128;
  const int lrow = l >> 2, lcol = l & 3;          // staging: 4 lanes x 16B per 64B row
  const int fr = l & 15, fk = (l >> 4) * 8;
  f4 acc[4][4] = {};

  for (int k0 = 0; k0 < K; k0 += 32) {
    for (int j = 0; j < 2; ++j) {
      int ra = w * 32 + j * 16;
      stage16(A  + (size_t)(m0 + ra + lrow) * K + k0 + lcol * 8, &As[ra * 32], l);
      stage16(Bt + (size_t)(n0 + ra + lrow) * K + k0 + lcol * 8, &Bs[ra * 32], l);
    }
    asm volatile("s_waitcnt vmcnt(0)" ::: "memory");
    __syncthreads();
    bf8 af[4], bfv[4];
#pragma unroll
    for (int i = 0; i < 4; ++i) af[i]  = *(const bf8*)&As[(wr * 64 + i * 16 + fr) * 32 + fk];
#pragma unroll
    for (int i = 0; i < 4; ++i) bfv[i] = *(const bf8*)&Bs[(wc * 64 + i * 16 + fr) * 32 + fk];
#pragma unroll
    for (int i = 0; i < 4; ++i)
#pragma unroll
      for (int j2 = 0; j2 < 4; ++j2)
        acc[i][j2] = mfma16(af[i], bfv[j2], acc[i][j2]);
    __syncthreads();
  }

  const int fg = l >> 4;
  if (MODE == 1) {
#pragma unroll
    for (int j2 = 0; j2 < 4; ++j2) {
      int col = n0 + wc * 64 + j2 * 16 + fr;
      float bv = bias[col];
#pragma unroll
      for (int i = 0; i < 4; ++i) {
        int rbase = m0 + wr * 64 + i * 16 + fg * 4;
#pragma unroll
        for (int r = 0; r < 4; ++r)
          __builtin_nontemporal_store(acc[i][j2][r] + bv, &outf[(size_t)(rbase + r) * 768 + col]);
      }
    }
  } else {
    // stage tile to LDS bf16 [128][136], then coalesced 16B stores per layout
#pragma unroll
    for (int j2 = 0; j2 < 4; ++j2) {
      int colc = wc * 64 + j2 * 16 + fr;
      float bv = bias[n0 + colc];
#pragma unroll
      for (int i = 0; i < 4; ++i)
#pragma unroll
        for (int r = 0; r < 4; ++r)
          sm[(wr * 64 + i * 16 + fg * 4 + r) * 136 + colc] = f2b(acc[i][j2][r] + bv);
    }
    __syncthreads();
#pragma unroll
    for (int it = 0; it < 8; ++it) {
      int flat = it * 2048 + tid * 8;
      int rl = flat >> 7, mc = flat & 127;
      int row = m0 + rl, col = n0 + mc;
      bf8 v = *(const bf8*)&sm[rl * 136 + mc];
      int b = row >> 11, n = row & 2047;
      unsigned short* dst;
      if (col < 768)        { int h = col >> 6;
        dst = qo + (((size_t)b * 12 + h) * 2048 + n) * 64 + (col & 63); }
      else if (col < 1536)  { int c2 = col - 768;  int h = c2 >> 6;
        dst = ko + (((size_t)b * 12 + h) * 2048 + n) * 64 + (c2 & 63); }
      else                  { int c2 = col - 1536; int h = c2 >> 6;
        dst = vo + (((size_t)b * 12 + h) * 2048 + n) * 64 + (c2 & 63); }
      *(bf8*)dst = v;
    }
  }
}

// ---------------- merged: P producer (bid<6144) | V transpose (else) ----------------
// pexp: S=QK^T GEMM, epilogue exp -> Pws bf16 + L partials (R9 body verbatim).
// trv: bf16 V[bh][2048][64] -> vT[bh][64][2048] (R9 body, LDS overlaid on sm).
__global__ __launch_bounds__(256) void k_pexptrv(
    const unsigned short* __restrict__ q,
    const unsigned short* __restrict__ kk,
    const float* __restrict__ maskbias,
    unsigned short* __restrict__ Pws,
    float* __restrict__ Lpart,
    const unsigned short* __restrict__ v,
    unsigned short* __restrict__ vT)
{
  __shared__ unsigned short sm[128 * 136];     // pexp: As/Bs + epilogue; trv: first 1056
  const int bid = blockIdx.x;
  const int tid = threadIdx.x;
  if (bid >= 6144) {
    // trv: id = bx + 2*by + 128*bz  (bx<2, by<64, bz<24)
    int id = bid - 6144;
    int bx = id & 1, by = (id >> 1) & 63, bz = id >> 7;
    int tx = tid & 31, ty = tid >> 5;
    const unsigned short* src = v + (size_t)bz * 131072;
    unsigned short* dst = vT + (size_t)bz * 131072;
    for (int j = 0; j < 32; j += 8)
      sm[(ty + j) * 33 + tx] = src[(size_t)(by * 32 + ty + j) * 64 + bx * 32 + tx];
    __syncthreads();
    for (int j = 0; j < 32; j += 8)
      dst[(size_t)(bx * 32 + ty + j) * 2048 + by * 32 + tx] = sm[tx * 33 + ty + j];
    return;
  }
  unsigned short* As = sm;
  unsigned short* Bs = sm + 4096;
  const int w = tid >> 6, l = tid & 63;
  const int wr = w >> 1, wc = w & 1;
  const int mt = bid & 15, nt = (bid >> 4) & 15, bh = bid >> 8;
  const int b = bh / 12;
  const int n0 = nt * 128, m0 = mt * 128;
  const int lrow = l >> 2, lcol = l & 3;
  const int fr = l & 15, fg = l >> 4, fk = fg * 8;
  const unsigned short* qh = q + (size_t)bh * 2048 * 64;
  const unsigned short* kh = kk + (size_t)bh * 2048 * 64;
  f4 acc[4][4] = {};

  for (int k0 = 0; k0 < 64; k0 += 32) {
    for (int j = 0; j < 2; ++j) {
      int ra = w * 32 + j * 16;
      stage16(qh + (size_t)(n0 + ra + lrow) * 64 + k0 + lcol * 8, &As[ra * 32], l);
      stage16(kh + (size_t)(m0 + ra + lrow) * 64 + k0 + lcol * 8, &Bs[ra * 32], l);
    }
    asm volatile("s_waitcnt vmcnt(0)" ::: "memory");
    __syncthreads();
    bf8 af[4], bfv[4];
#pragma unroll
    for (int i = 0; i < 4; ++i) af[i]  = *(const bf8*)&As[(wr * 64 + i * 16 + fr) * 32 + fk];
#pragma unroll
    for (int i = 0; i < 4; ++i) bfv[i] = *(const bf8*)&Bs[(wc * 64 + i * 16 + fr) * 32 + fk];
#pragma unroll
    for (int i = 0; i < 4; ++i)
#pragma unroll
      for (int j2 = 0; j2 < 4; ++j2)
        acc[i][j2] = mfma16(af[i], bfv[j2], acc[i][j2]);
    __syncthreads();
  }

  // epilogue: p = exp(s*scale + mb); stage into sm[128][136]; row-sum -> Lpart
  const float scale = 0.125f;
  const float* mbp = maskbias + b * 2048 + m0;
#pragma unroll
  for (int i = 0; i < 4; ++i) {
#pragma unroll
    for (int r = 0; r < 4; ++r) {
      int nl = wr * 64 + i * 16 + fg * 4 + r;
      float rs = 0.0f;
#pragma unroll
      for (int j2 = 0; j2 < 4; ++j2) {
        int ml = wc * 64 + j2 * 16 + fr;
        float p = __expf(fmaf(acc[i][j2][r], scale, mbp[ml]));
        rs += p;
        sm[nl * 136 + ml] = f2b(p);
      }
      rs += __shfl_xor(rs, 1);
      rs += __shfl_xor(rs, 2);
      rs += __shfl_xor(rs, 4);
      rs += __shfl_xor(rs, 8);
      if (fr == 0)
        Lpart[((size_t)bh * 32 + mt * 2 + wc) * 2048 + n0 + nl] = rs;
    }
  }
  __syncthreads();
  // coalesced bf16 write: 8 iters x 256 thr x 8 shorts = 128x128 tile
#pragma unroll
  for (int it = 0; it < 8; ++it) {
    int flat = it * 2048 + tid * 8;
    int row = flat >> 7, mc = flat & 127;
    bf8 vv = *(const bf8*)&sm[row * 136 + mc];
    *(bf8*)(Pws + ((size_t)bh * 2048 + n0 + row) * 2048 + m0 + mc) = vv;
  }
}

// ---------------- reduce 32 L slices -> iL ----------------
__global__ void k_lred(const float* __restrict__ Lpart, float* __restrict__ iLst) {
  int t = blockIdx.x * 256 + threadIdx.x;   // 49152 = 24 bh x 2048 n
  int bh = t >> 11, n = t & 2047;
  float s = 0.0f;
#pragma unroll
  for (int sl = 0; sl < 32; ++sl)
    s += Lpart[((size_t)bh * 32 + sl) * 2048 + n];
  iLst[t] = 1.0f / fmaxf(s, 1e-30f);
}

// ---------------- merged: PV (bid<768) | att writer (else) ----------------
// pv blocks dispatched FIRST -> resident from t=0, MFMA overlaps attw's BW streaming.
// att stores NONTEMPORAL: att is write-once/never-read; keep its 402MB stream out
// of L3 so Pws (201MB, read twice right after being written) stays L3-resident.
__global__ __launch_bounds__(256) void k_attwpv(
    const unsigned short* __restrict__ Pws,
    const float* __restrict__ iLst,
    float* __restrict__ att,
    const unsigned short* __restrict__ vT,
    unsigned short* __restrict__ ao)
{
  __shared__ unsigned short smem[6656];
  const int bid = blockIdx.x;
  const int tid = threadIdx.x;
  const int w = tid >> 6, l = tid & 63;

  if (bid < 768) {
    // ---- PV: O = P @ V, ks=1, iL folded, writes ao bf16 directly ----
    unsigned short* B0 = smem;            // [64*32]
    unsigned short* B1 = smem + 2048;     // [64*32]
    const int bh = bid % 24, nt = bid / 24;
    const int b = bh / 12, h = bh % 12;
    const int n0 = nt * 64;
    const int lr = l >> 2, lc = (l & 3) * 8;
    const int fr = l & 15, fg = l >> 4, fk = fg * 8;
    const unsigned short* Ph = Pws + (size_t)bh * 2048 * 2048
                             + (size_t)(n0 + w * 16 + fr) * 2048 + fk;
    const unsigned short* vh = vT + (size_t)bh * 64 * 2048;
    f4 acc[4] = {};

    for (int k0 = 0; k0 < 2048; k0 += 64) {
      stage16(vh + (size_t)(w * 16 + lr) * 2048 + k0 + lc,      &B0[(w * 16) * 32], l);
      stage16(vh + (size_t)(w * 16 + lr) * 2048 + k0 + 32 + lc, &B1[(w * 16) * 32], l);
      bf8 a0 = *(const bf8*)(Ph + k0);
      bf8 a1 = *(const bf8*)(Ph + k0 + 32);
      asm volatile("s_waitcnt vmcnt(0)" ::: "memory");
      __syncthreads();
#pragma unroll
      for (int j2 = 0; j2 < 4; ++j2) {
        bf8 bv = *(const bf8*)&B0[(j2 * 16 + fr) * 32 + fk];
        acc[j2] = mfma16(a0, bv, acc[j2]);
      }
#pragma unroll
      for (int j2 = 0; j2 < 4; ++j2) {
        bf8 bv = *(const bf8*)&B1[(j2 * 16 + fr) * 32 + fk];
        acc[j2] = mfma16(a1, bv, acc[j2]);
      }
      __syncthreads();
    }

    float il[4];
#pragma unroll
    for (int r = 0; r < 4; ++r)
      il[r] = iLst[(size_t)bh * 2048 + n0 + w * 16 + fg * 4 + r];
#pragma unroll
    for (int j2 = 0; j2 < 4; ++j2)
#pragma unroll
      for (int r = 0; r < 4; ++r)
        ao[((size_t)(b * 2048) + n0 + w * 16 + fg * 4 + r) * 768 + h * 64 + j2 * 16 + fr]
            = f2b(acc[j2][r] * il[r]);
    return;
  }

  // ---- att writer: barrier-free transpose-stream, bf16 slab ----
  const int idx = (bid - 768) * 4 + w;      // = b*4096 + n*2 + half
  const int b = idx >> 12;
  const int n = (idx >> 1) & 2047;
  const int half = idx & 1;
  const int hq = l >> 4, mg = l & 15;
  unsigned short* sl = smem + w * 1664;

  float iLv[3];
#pragma unroll
  for (int g = 0; g < 3; ++g)
    iLv[g] = iLst[((size_t)(b * 12 + g * 4 + hq)) * 2048 + n];

  for (int c = 0; c < 8; ++c) {
    const int m0 = half * 1024 + c * 128;
#pragma unroll
    for (int g = 0; g < 3; ++g) {
      int h = g * 4 + hq;
      bf8 pv = *(const bf8*)(Pws + ((size_t)(b * 12 + h) * 2048 + n) * 2048 + m0 + mg * 8);
      const unsigned short* pu = (const unsigned short*)&pv;
      // element (m, h) at sl[(m>>3)*104 + (m&7)*12 + h]; m = mg*8+j
#pragma unroll
      for (int j = 0; j < 8; ++j)
        sl[mg * 104 + j * 12 + h] = f2b(b2f(pu[j]) * iLv[g]);
    }
    // same-wave LDS RAW: compiler inserts lgkmcnt waits
    float* dst = att + (((size_t)(b * 2048 + n)) * 2048 + m0) * 12;
#pragma unroll
    for (int it = 0; it < 6; ++it) {
      int f = it * 256 + l * 4;
      int sa = (f / 96) * 104 + f % 96;
      ushort4 s4 = *(const ushort4*)&sl[sa];
      f4 v = {b2f(s4.x), b2f(s4.y), b2f(s4.z), b2f(s4.w)};
      __builtin_nontemporal_store(v, (f4*)(dst + f));
    }
  }
}

extern "C" void kernel_launch(void* const* d_in, const int* in_sizes, int n_in,
                              void* d_out, int out_size, void* d_ws, size_t ws_size,
                              hipStream_t stream) {
  const float* x   = (const float*)d_in[0];
  const void*  msk = d_in[1];
  const float* Wq  = (const float*)d_in[2];
  const float* bq  = (const float*)d_in[3];
  const float* Wkv = (const float*)d_in[4];
  const float* bkv = (const float*)d_in[5];
  const float* Wp  = (const float*)d_in[6];
  const float* bp  = (const float*)d_in[7];
  float* out = (float*)d_out;
  float* att = out + (size_t)2 * 2048 * 768;

  char* ws = (char*)d_ws;
  float* maskbias = (float*)ws;                      // 4096 f32
  float* biasc    = maskbias + 4096;                 // 2304 f32
  unsigned short* xb  = (unsigned short*)(ws + 32768);
  unsigned short* Wct = xb  + (size_t)4096 * 768;    // [2304][768]
  unsigned short* Wpt = Wct + (size_t)2304 * 768;    // [768][768]
  unsigned short* qb  = Wpt + (size_t)768 * 768;     // [2][12][2048][64]
  unsigned short* kb  = qb  + (size_t)3145728;
  unsigned short* vb  = kb  + (size_t)3145728;       // [2][12][2048][64]
  unsigned short* vTb = vb  + (size_t)3145728;       // [2][12][64][2048]
  float* iLstat = (float*)(vTb + (size_t)3145728);   // [24][2048]
  float* Lpart  = iLstat + 49152;                    // [24][32][2048] f32, 6.3MB
  unsigned short* Pws = (unsigned short*)(Lpart + (size_t)24 * 32 * 2048); // [24][2048][2048] bf16, 201MB
  unsigned short* ao = xb;                           // overlay: xb dead after k_gemm<0>

  k_prept<<<dim3(5401), dim3(256), 0, stream>>>(x, xb, msk, bq, bkv, maskbias, biasc,
                                                Wq, Wkv, Wp, Wct, Wpt);
  k_gemm<0><<<dim3(18, 32), dim3(256), 0, stream>>>(xb, Wct, biasc, nullptr, qb, kb, vb, 768);
  k_pexptrv<<<dim3(9216), dim3(256), 0, stream>>>(qb, kb, maskbias, Pws, Lpart, vb, vTb);
  k_lred<<<dim3(192), dim3(256), 0, stream>>>(Lpart, iLstat);
  k_attwpv<<<dim3(2816), dim3(256), 0, stream>>>(Pws, iLstat, att, vTb, ao);
  k_gemm<1><<<dim3(6, 32), dim3(256), 0, stream>>>(ao, Wpt, bp, out, nullptr, nullptr, nullptr, 768);
}